// Round 8
// baseline (1246.967 us; speedup 1.0000x reference)
//
#include <hip/hip_runtime.h>
#include <cstddef>
#include <cstdint>

#define N_NODES 20000
#define N_EDGES 320000
#define E_TOT   (N_EDGES + N_NODES)   // 340000
#define HEADS   16

typedef __bf16 bf16;
typedef __attribute__((ext_vector_type(8))) __bf16 bf16x8;
typedef __attribute__((ext_vector_type(4))) __bf16 bf16x4;
typedef __attribute__((ext_vector_type(4))) float  f32x4;

__device__ __forceinline__ void gll16(const void* g, void* l) {
    __builtin_amdgcn_global_load_lds(
        (const __attribute__((address_space(1))) unsigned int*)g,
        (__attribute__((address_space(3))) unsigned int*)l, 16, 0, 0);
}

// ---------------------------------------------------------------------------
// Layer 1: x[N,3] @ W[3,1024] -> hgat bf16, fused alpha_s/alpha_d.
__global__ __launch_bounds__(256)
void k_lin1(const float* __restrict__ x, const float* __restrict__ W,
            const float* __restrict__ aS, const float* __restrict__ aD,
            bf16* __restrict__ hg, float* __restrict__ as_,
            float* __restrict__ ad_) {
    int n = blockIdx.x;
    int t = threadIdx.x;
    int f0 = t * 4, hd = t >> 4;
    float x0 = x[n*3+0], x1 = x[n*3+1], x2 = x[n*3+2];
    float v[4];
    bf16x4 hv;
#pragma unroll
    for (int c = 0; c < 4; ++c) {
        int f = f0 + c;
        v[c] = x0*W[f] + x1*W[1024+f] + x2*W[2048+f];
        hv[c] = (bf16)v[c];
    }
    *reinterpret_cast<bf16x4*>(&hg[(size_t)n * 1024 + f0]) = hv;
    float ps = 0.f, pd = 0.f;
    int cb = (t & 15) * 4;
#pragma unroll
    for (int c = 0; c < 4; ++c) {
        ps = fmaf(v[c], aS[hd*64 + cb + c], ps);
        pd = fmaf(v[c], aD[hd*64 + cb + c], pd);
    }
#pragma unroll
    for (int off = 1; off < 16; off <<= 1) {
        ps += __shfl_xor(ps, off);
        pd += __shfl_xor(pd, off);
    }
    if ((t & 15) == 0) {
        as_[n*16 + hd] = ps;
        ad_[n*16 + hd] = pd;
    }
}

// ---------------------------------------------------------------------------
// W [1024][M] fp32 -> Wt_hi (+ optional Wt_lo) [M][1024] bf16
__global__ __launch_bounds__(256)
void k_convW(const float* __restrict__ W, bf16* __restrict__ Th,
             bf16* __restrict__ Tl, int M) {
    __shared__ float t[32][33];
    int m0 = blockIdx.x * 32, k0 = blockIdx.y * 32;
    int j = threadIdx.x & 31, i0 = threadIdx.x >> 5;
#pragma unroll
    for (int s = 0; s < 4; ++s) {
        int i = i0 + s * 8;
        t[i][j] = W[(size_t)(k0 + i) * M + m0 + j];
    }
    __syncthreads();
#pragma unroll
    for (int s = 0; s < 4; ++s) {
        int i = i0 + s * 8;
        float v = t[j][i];
        bf16 hi = (bf16)v;
        Th[(size_t)(m0 + i) * 1024 + k0 + j] = hi;
        if (Tl) Tl[(size_t)(m0 + i) * 1024 + k0 + j] = (bf16)(v - (float)hi);
    }
}

// ---------------------------------------------------------------------------
// MFMA GEMM: C = A_bf16 * (Bh [+ Bl]).  blockIdx.x = COL block (XCD-pinned B).
// FUSE: alpha epilogue (C=64 layers), no fp32 C write.  TWOB: B hi+lo 2-pass.
template<bool FUSE, bool TWOB>
__global__ __launch_bounds__(256, 2)
void k_gemm3(const bf16* __restrict__ Ah,
             const bf16* __restrict__ Bh, const bf16* __restrict__ Bl,
             float* __restrict__ Cf, bf16* __restrict__ Ch,
             const float* __restrict__ aS, const float* __restrict__ aD,
             float* __restrict__ as_, float* __restrict__ ad_,
             int N, int M) {
    __shared__ __align__(16) bf16 sAh[128 * 32];
    __shared__ __align__(16) bf16 sBh[128 * 32];
    __shared__ __align__(16) bf16 sBl[TWOB ? 128 * 32 : 8];

    const int tid  = threadIdx.x;
    const int wid  = tid >> 6, lane = tid & 63;
    const int wr   = wid >> 1, wc = wid & 1;
    const int col0 = blockIdx.x * 128, row0 = blockIdx.y * 128;

    f32x4 acc[4][4] = {};

    const int rl = lane >> 2;
    const int gg = lane & 3;
    const int rb0 = wid * 32;
    const int lrow = lane & 15, g4 = lane >> 4;

    for (int k0 = 0; k0 < 1024; k0 += 32) {
#pragma unroll
        for (int half = 0; half < 2; ++half) {
            int rt = rb0 + half * 16 + rl;
            int kc = (gg ^ ((rt >> 1) & 3)) * 8;
            size_t lbase = (size_t)(rb0 + half * 16) * 32;
            int ar = row0 + rt; if (ar >= N) ar = N - 1;
            gll16(Ah + (size_t)ar * 1024 + k0 + kc, sAh + lbase);
            int br = col0 + rt;
            gll16(Bh + (size_t)br * 1024 + k0 + kc, sBh + lbase);
            if (TWOB) gll16(Bl + (size_t)br * 1024 + k0 + kc, sBl + lbase);
        }
        __syncthreads();

        bf16x8 ah[4], bh[4], bl[4];
#pragma unroll
        for (int m = 0; m < 4; ++m) {
            int r = wr * 64 + m * 16 + lrow;
            int off = r * 32 + ((g4 ^ ((r >> 1) & 3)) * 8);
            ah[m] = *(const bf16x8*)&sAh[off];
        }
#pragma unroll
        for (int n = 0; n < 4; ++n) {
            int r = wc * 64 + n * 16 + lrow;
            int off = r * 32 + ((g4 ^ ((r >> 1) & 3)) * 8);
            bh[n] = *(const bf16x8*)&sBh[off];
            if (TWOB) bl[n] = *(const bf16x8*)&sBl[off];
        }
#pragma unroll
        for (int m = 0; m < 4; ++m)
#pragma unroll
            for (int n = 0; n < 4; ++n) {
                acc[m][n] = __builtin_amdgcn_mfma_f32_16x16x32_bf16(ah[m], bh[n], acc[m][n], 0, 0, 0);
                if (TWOB)
                    acc[m][n] = __builtin_amdgcn_mfma_f32_16x16x32_bf16(ah[m], bl[n], acc[m][n], 0, 0, 0);
            }
        __syncthreads();
    }

    // C/D layout: col=lane&15 (lrow), row=(lane>>4)*4+q (g4,q)
#pragma unroll
    for (int m = 0; m < 4; ++m) {
#pragma unroll
        for (int n = 0; n < 4; ++n) {
            int col = col0 + wc * 64 + n * 16 + lrow;
#pragma unroll
            for (int q = 0; q < 4; ++q) {
                int row = row0 + wr * 64 + m * 16 + g4 * 4 + q;
                if (row < N) {
                    float v = acc[m][n][q];
                    if (!FUSE) Cf[(size_t)row * M + col] = v;
                    Ch[(size_t)row * M + col] = (bf16)v;
                }
            }
        }
    }

    if (FUSE) {
        const int hd = blockIdx.x * 2 + wc;
        float asv[4], adv[4];
#pragma unroll
        for (int n = 0; n < 4; ++n) {
            asv[n] = aS[hd * 64 + n * 16 + lrow];
            adv[n] = aD[hd * 64 + n * 16 + lrow];
        }
        float ps[4][4], pd[4][4];
#pragma unroll
        for (int m = 0; m < 4; ++m)
#pragma unroll
            for (int q = 0; q < 4; ++q) {
                float s = 0.f, d = 0.f;
#pragma unroll
                for (int n = 0; n < 4; ++n) {
                    s = fmaf(acc[m][n][q], asv[n], s);
                    d = fmaf(acc[m][n][q], adv[n], d);
                }
                ps[m][q] = s; pd[m][q] = d;
            }
#pragma unroll
        for (int off = 1; off < 16; off <<= 1) {
#pragma unroll
            for (int m = 0; m < 4; ++m)
#pragma unroll
                for (int q = 0; q < 4; ++q) {
                    ps[m][q] += __shfl_xor(ps[m][q], off);
                    pd[m][q] += __shfl_xor(pd[m][q], off);
                }
        }
        if (lrow == 0) {
#pragma unroll
            for (int m = 0; m < 4; ++m)
#pragma unroll
                for (int q = 0; q < 4; ++q) {
                    int row = row0 + wr * 64 + m * 16 + g4 * 4 + q;
                    if (row < N) {
                        as_[row * 16 + hd] = ps[m][q];
                        ad_[row * 16 + hd] = pd[m][q];
                    }
                }
        }
    }
}

// ---------------------------------------------------------------------------
// alpha for layer 6 only (C=48): one wave per (node, head)
__global__ __launch_bounds__(256)
void k_alpha(const float* __restrict__ h, const float* __restrict__ a_s,
             const float* __restrict__ a_d, float* __restrict__ as_out,
             float* __restrict__ ad_out, int C, int M) {
    int pair = blockIdx.x * 4 + (threadIdx.x >> 6);
    int lane = threadIdx.x & 63;
    if (pair >= N_NODES * HEADS) return;
    int n = pair >> 4, hd = pair & 15;
    float vs = 0.f, vd = 0.f;
    if (lane < C) {
        float hv = h[(size_t)n * M + hd * C + lane];
        vs = hv * a_s[hd * C + lane];
        vd = hv * a_d[hd * C + lane];
    }
#pragma unroll
    for (int off = 32; off > 0; off >>= 1) {
        vs += __shfl_down(vs, off);
        vd += __shfl_down(vd, off);
    }
    if (lane == 0) { as_out[pair] = vs; ad_out[pair] = vd; }
}

// ---------------------------------------------------------------------------
// CSR build
__global__ void k_zero_i(int* __restrict__ p, int n) {
    int t = blockIdx.x * 256 + threadIdx.x;
    if (t < n) p[t] = 0;
}
__global__ void k_hist(const int* __restrict__ ei, int* __restrict__ deg) {
    int e = blockIdx.x * 256 + threadIdx.x;
    if (e >= E_TOT) return;
    int d = (e < N_EDGES) ? ei[N_EDGES + e] : e - N_EDGES;
    atomicAdd(&deg[d], 1);
}
__global__ __launch_bounds__(256)
void k_scan(const int* __restrict__ deg, int* __restrict__ rowstart,
            int* __restrict__ cursor) {
    __shared__ int sh[256];
    int carry = 0;
    for (int base = 0; base < N_NODES; base += 256) {
        int i = base + threadIdx.x;
        int v = (i < N_NODES) ? deg[i] : 0;
        sh[threadIdx.x] = v;
        __syncthreads();
        for (int off = 1; off < 256; off <<= 1) {
            int t = (threadIdx.x >= off) ? sh[threadIdx.x - off] : 0;
            __syncthreads();
            sh[threadIdx.x] += t;
            __syncthreads();
        }
        if (i < N_NODES) {
            int excl = carry + sh[threadIdx.x] - v;
            rowstart[i] = excl;
            cursor[i] = excl;
        }
        carry += sh[255];
        __syncthreads();
    }
    if (threadIdx.x == 0) rowstart[N_NODES] = carry;
}
__global__ void k_scatter(const int* __restrict__ ei, int* __restrict__ cursor,
                          int* __restrict__ csr_src) {
    int e = blockIdx.x * 256 + threadIdx.x;
    if (e >= E_TOT) return;
    int s, d;
    if (e < N_EDGES) { s = ei[e]; d = ei[N_EDGES + e]; }
    else             { s = d = e - N_EDGES; }
    int slot = atomicAdd(&cursor[d], 1);
    csr_src[slot] = s;
}

// ---------------------------------------------------------------------------
// degree counting sort: perm = nodes ordered by degree (ties arbitrary)
__global__ void k_dhist(const int* __restrict__ deg, int* __restrict__ bins) {
    int n = blockIdx.x * 256 + threadIdx.x;
    if (n >= N_NODES) return;
    int d = deg[n]; if (d > 255) d = 255;
    atomicAdd(&bins[d], 1);
}
__global__ __launch_bounds__(256)
void k_dscan(const int* __restrict__ bins, int* __restrict__ cur) {
    __shared__ int sh[256];
    int v = bins[threadIdx.x];
    sh[threadIdx.x] = v;
    __syncthreads();
    for (int off = 1; off < 256; off <<= 1) {
        int t = (threadIdx.x >= off) ? sh[threadIdx.x - off] : 0;
        __syncthreads();
        sh[threadIdx.x] += t;
        __syncthreads();
    }
    cur[threadIdx.x] = sh[threadIdx.x] - v;   // exclusive
}
__global__ void k_dscatter(const int* __restrict__ deg, int* __restrict__ cur,
                           int* __restrict__ perm) {
    int n = blockIdx.x * 256 + threadIdx.x;
    if (n >= N_NODES) return;
    int d = deg[n]; if (d > 255) d = 255;
    int slot = atomicAdd(&cur[d], 1);
    perm[slot] = n;
}

// ---------------------------------------------------------------------------
// aggregation M=1024: online softmax with DEFER-MAX + depth-2 prefetch,
// degree-sorted nodes.  grid (8, 1250): x = 128-col slice (XCD-pinned),
// block = 16 nodes x 16 threads, 8 cols/thread.
__global__ __launch_bounds__(256)
void k_agg1024(const bf16* __restrict__ hg, const int* __restrict__ rowstart,
               const int* __restrict__ csr_src, const int* __restrict__ perm,
               const float* __restrict__ as_, const float* __restrict__ ad_,
               const float* __restrict__ bias, bf16* __restrict__ oh) {
    int n = perm[blockIdx.y * 16 + (threadIdx.x >> 4)];
    int sub = threadIdx.x & 15;
    int f0 = blockIdx.x * 128 + sub * 8;
    int hd = f0 >> 6;
    int s0 = rowstart[n], s1 = rowstart[n + 1];
    float adv = ad_[n * 16 + hd];

    // prefetch pipeline: cur = edge j, s_nxt = src of edge j+1
    int s_cur = csr_src[s0];
    float as_cur = as_[s_cur * 16 + hd];
    bf16x8 hv_cur = *reinterpret_cast<const bf16x8*>(&hg[(size_t)s_cur * 1024 + f0]);
    int jn = (s0 + 1 < s1) ? s0 + 1 : s1 - 1;
    int s_nxt = csr_src[jn];

    float m = -1e30f, den = 0.f;
    float acc[8] = {};
    for (int j = s0; j < s1; ++j) {
        int j2 = (j + 2 < s1) ? j + 2 : s1 - 1;
        int s_n2 = csr_src[j2];
        float as_nxt = as_[s_nxt * 16 + hd];
        bf16x8 hv_nxt = *reinterpret_cast<const bf16x8*>(&hg[(size_t)s_nxt * 1024 + f0]);

        float v = as_cur + adv;
        v = v > 0.f ? v : 0.2f * v;
        if (v <= m) {                       // common path: no rescale
            float re = __expf(v - m);
            den += re;
#pragma unroll
            for (int c = 0; c < 8; ++c)
                acc[c] = fmaf(re, (float)hv_cur[c], acc[c]);
        } else {                            // rescale path: re = 1 exactly
            float rm = __expf(m - v);
            den = fmaf(den, rm, 1.f);
#pragma unroll
            for (int c = 0; c < 8; ++c)
                acc[c] = fmaf(acc[c], rm, (float)hv_cur[c]);
            m = v;
        }
        s_cur = s_nxt; as_cur = as_nxt; hv_cur = hv_nxt; s_nxt = s_n2;
    }
    float inv = 1.f / (den + 1e-16f);
    bf16x8 vh;
#pragma unroll
    for (int c = 0; c < 8; ++c) {
        float r = fmaxf(fmaf(acc[c], inv, bias[f0 + c]), 0.f);
        vh[c] = (bf16)r;
    }
    *reinterpret_cast<bf16x8*>(&oh[(size_t)n * 1024 + f0]) = vh;
}

// last layer M=768 (C=48): same structure, fp32 out, no relu
__global__ __launch_bounds__(256)
void k_agg768(const bf16* __restrict__ hg, const int* __restrict__ rowstart,
              const int* __restrict__ csr_src, const int* __restrict__ perm,
              const float* __restrict__ as_, const float* __restrict__ ad_,
              const float* __restrict__ bias, float* __restrict__ out) {
    int n = perm[blockIdx.x * 2 + (threadIdx.x >> 7)];
    int tloc = threadIdx.x & 127;
    if (tloc >= 96) return;
    int f0 = tloc * 8;
    int hd = f0 / 48;
    int s0 = rowstart[n], s1 = rowstart[n + 1];
    float adv = ad_[n * 16 + hd];

    int s_cur = csr_src[s0];
    float as_cur = as_[s_cur * 16 + hd];
    bf16x8 hv_cur = *reinterpret_cast<const bf16x8*>(&hg[(size_t)s_cur * 768 + f0]);
    int jn = (s0 + 1 < s1) ? s0 + 1 : s1 - 1;
    int s_nxt = csr_src[jn];

    float m = -1e30f, den = 0.f;
    float acc[8] = {};
    for (int j = s0; j < s1; ++j) {
        int j2 = (j + 2 < s1) ? j + 2 : s1 - 1;
        int s_n2 = csr_src[j2];
        float as_nxt = as_[s_nxt * 16 + hd];
        bf16x8 hv_nxt = *reinterpret_cast<const bf16x8*>(&hg[(size_t)s_nxt * 768 + f0]);

        float v = as_cur + adv;
        v = v > 0.f ? v : 0.2f * v;
        if (v <= m) {
            float re = __expf(v - m);
            den += re;
#pragma unroll
            for (int c = 0; c < 8; ++c)
                acc[c] = fmaf(re, (float)hv_cur[c], acc[c]);
        } else {
            float rm = __expf(m - v);
            den = fmaf(den, rm, 1.f);
#pragma unroll
            for (int c = 0; c < 8; ++c)
                acc[c] = fmaf(acc[c], rm, (float)hv_cur[c]);
            m = v;
        }
        s_cur = s_nxt; as_cur = as_nxt; hv_cur = hv_nxt; s_nxt = s_n2;
    }
    float inv = 1.f / (den + 1e-16f);
#pragma unroll
    for (int c = 0; c < 8; ++c)
        out[(size_t)n * 768 + f0 + c] = fmaf(acc[c], inv, bias[f0 + c]);
}

// ---------------------------------------------------------------------------
// final: out[1,768] = sum_n x[n, :]
__global__ __launch_bounds__(256)
void k_colsum(const float* __restrict__ x, float* __restrict__ out) {
    int f = blockIdx.x * 256 + threadIdx.x;
    int chunk = blockIdx.y;
    int n0 = chunk * 625, n1 = n0 + 625;
    float s = 0.f;
    for (int n = n0; n < n1; ++n) s += x[(size_t)n * 768 + f];
    atomicAdd(&out[f], s);
}

// ---------------------------------------------------------------------------
extern "C" void kernel_launch(void* const* d_in, const int* in_sizes, int n_in,
                              void* d_out, int out_size, void* d_ws, size_t ws_size,
                              hipStream_t stream) {
    const float* x0 = (const float*)d_in[0];
    const int*   ei = (const int*)d_in[1];

    char* w = (char*)d_ws;
    float* xB  = (float*)w;                       // layer-6 fp32 C [N,1024 alloc]
    float* xOut = (float*)w;                      // alias: layer-6 agg out [N,768] fp32
    w += (size_t)N_NODES * 1024 * sizeof(float);  // 80 MB region covers both uses
    bf16*  hgat = (bf16*)w; w += (size_t)N_NODES * 1024 * sizeof(bf16);
    bf16*  x_hi = (bf16*)w; w += (size_t)N_NODES * 1024 * sizeof(bf16);
    float* as_  = (float*)w; w += (size_t)N_NODES * HEADS * sizeof(float);
    float* ad_  = (float*)w; w += (size_t)N_NODES * HEADS * sizeof(float);
    bf16* Wt_hi = (bf16*)w; w += (size_t)1024 * 1024 * sizeof(bf16);
    bf16* Wt_lo = (bf16*)w; w += (size_t)1024 * 1024 * sizeof(bf16);
    int* deg      = (int*)w; w += N_NODES * sizeof(int);
    int* rowstart = (int*)w; w += (N_NODES + 1) * sizeof(int);
    int* cursor   = (int*)w; w += N_NODES * sizeof(int);
    int* csr_src  = (int*)w; w += E_TOT * sizeof(int);
    int* dbins    = (int*)w; w += 256 * sizeof(int);
    int* dcur     = (int*)w; w += 256 * sizeof(int);
    int* perm     = (int*)w; w += N_NODES * sizeof(int);

    // ---- CSR build + degree sort (once) ----
    k_zero_i<<<(N_NODES + 255) / 256, 256, 0, stream>>>(deg, N_NODES);
    k_hist<<<(E_TOT + 255) / 256, 256, 0, stream>>>(ei, deg);
    k_scan<<<1, 256, 0, stream>>>(deg, rowstart, cursor);
    k_scatter<<<(E_TOT + 255) / 256, 256, 0, stream>>>(ei, cursor, csr_src);
    k_zero_i<<<1, 256, 0, stream>>>(dbins, 256);
    k_dhist<<<(N_NODES + 255) / 256, 256, 0, stream>>>(deg, dbins);
    k_dscan<<<1, 256, 0, stream>>>(dbins, dcur);
    k_dscatter<<<(N_NODES + 255) / 256, 256, 0, stream>>>(deg, dcur, perm);

    for (int l = 0; l < 6; ++l) {
        const float* W  = (const float*)d_in[2 + 4 * l + 0];
        const float* aS = (const float*)d_in[2 + 4 * l + 1];
        const float* aD = (const float*)d_in[2 + 4 * l + 2];
        const float* bv = (const float*)d_in[2 + 4 * l + 3];
        int M = (l == 5) ? 768 : 1024;

        if (l == 0) {
            k_lin1<<<N_NODES, 256, 0, stream>>>(x0, W, aS, aD, hgat, as_, ad_);
        } else {
            dim3 tg(M / 32, 32);
            dim3 grid(M / 128, (N_NODES + 127) / 128);   // x = COL block
            if (l < 5) {
                k_convW<<<tg, 256, 0, stream>>>(W, Wt_hi, nullptr, M);
                k_gemm3<true, false><<<grid, 256, 0, stream>>>(
                    x_hi, Wt_hi, nullptr, nullptr, hgat, aS, aD, as_, ad_,
                    N_NODES, M);
            } else {
                k_convW<<<tg, 256, 0, stream>>>(W, Wt_hi, Wt_lo, M);
                k_gemm3<false, true><<<grid, 256, 0, stream>>>(
                    x_hi, Wt_hi, Wt_lo, xB, hgat, nullptr, nullptr,
                    nullptr, nullptr, N_NODES, M);
                k_alpha<<<(N_NODES * HEADS + 3) / 4, 256, 0, stream>>>(
                    xB, aS, aD, as_, ad_, 48, 768);
            }
        }
        if (l < 5) {
            dim3 agrid(8, N_NODES / 16);
            k_agg1024<<<agrid, 256, 0, stream>>>(
                hgat, rowstart, csr_src, perm, as_, ad_, bv, x_hi);
        } else {
            k_agg768<<<N_NODES / 2, 256, 0, stream>>>(
                hgat, rowstart, csr_src, perm, as_, ad_, bv, xOut);
        }
    }

    hipMemsetAsync(d_out, 0, (size_t)out_size * sizeof(float), stream);
    dim3 cgrid(3, 32);
    k_colsum<<<cgrid, 256, 0, stream>>>(xOut, (float*)d_out);
}